// Round 2
// baseline (567.653 us; speedup 1.0000x reference)
//
#include <hip/hip_runtime.h>
#include <hip/hip_fp16.h>
#include <stdint.h>

#define B_TOT 131072
#define CHUNK 65536
#define NH 16
#define NC 32
#define HIDD 512

typedef unsigned short u16;
typedef __attribute__((ext_vector_type(8))) short short8;
typedef __attribute__((ext_vector_type(4))) float f32x4;
typedef __attribute__((ext_vector_type(4))) int i32x4;

#define GLLDS(g, l) __builtin_amdgcn_global_load_lds((const __attribute__((address_space(1))) unsigned int*)(g), (__attribute__((address_space(3))) unsigned int*)(l), 16, 0, 0)

__device__ __forceinline__ u16 f2bf(float x){
  unsigned u = __float_as_uint(x);
  u += 0x7fffu + ((u >> 16) & 1u);
  return (u16)(u >> 16);
}
__device__ __forceinline__ float bf2f(u16 b){ return __uint_as_float(((unsigned)b) << 16); }
__device__ __forceinline__ u16 f2h(float x){ __half h = __float2half(x); return *(u16*)&h; }
__device__ __forceinline__ float h2f(u16 b){ __half h; *(u16*)&h = b; return __half2float(h); }
// mish(x) = x*tanh(softplus(x)); tanh(log(1+e^x)) == (u^2-1)/(u^2+1), u = 1+e^x (exact identity)
__device__ __forceinline__ float mishf(float x){
  float e = __expf(fminf(x, 30.f));
  float u = 1.f + e;
  float u2 = u * u;
  return x * (u2 - 1.f) / (u2 + 1.f);
}

// ---------------- prep kernels ----------------
__global__ void prep_small(const float* __restrict__ deltas, const float* __restrict__ Wa,
                           const float* __restrict__ Wo, float* __restrict__ cps, float* __restrict__ wWo)
{
  const int t = threadIdx.x;
  if (t < NH){
    float cum[NC];
    float run = 0.f;
#pragma unroll
    for (int c = 0; c < NC; c++){
      float d = deltas[t*NC + c];
      float sp = (d > 20.f) ? d : log1pf(__expf(d));
      run += sp; cum[c] = run;
    }
    float s = 365.0f / run;
#pragma unroll
    for (int c = 0; c < NC; c++) cps[t*NC + c] = cum[c] * s;
  } else if (t >= 64 && t < 128){
    const int k = t - 64;
    float s = 0.f;
    for (int n = 0; n < HIDD; n++) s += Wa[k*HIDD + n] * Wo[n];
    wWo[k] = s;
  }
}

__global__ void prep_convert(const float* __restrict__ Wah, const float* __restrict__ Waa,
                             const float* __restrict__ Wb, const float* __restrict__ Wh,
                             u16* __restrict__ WahT, u16* __restrict__ WaaT,
                             u16* __restrict__ WbT, u16* __restrict__ WhT)
{
  int i = blockIdx.x * 256 + threadIdx.x;
  if (i < 262144){ int n = i >> 9, k = i & 511; WahT[i] = f2bf(Wah[k*512 + n]); return; }
  i -= 262144;
  if (i < 262144){ int n = i >> 9, k = i & 511; WaaT[i] = f2bf(Waa[k*512 + n]); return; }
  i -= 262144;
  if (i < 32768){ int n = i >> 6, k = i & 63; WbT[i] = f2bf(Wb[k*512 + n]); return; }
  i -= 32768;
  if (i < 16384){ int h = i >> 10, r = i & 1023, d = r >> 5, c = r & 31;
                  WhT[i] = f2bf(Wh[h*1024 + c*32 + d]); return; }
}

// ---------------- stage 1: feats -> LN -> softmax -> einsum(MFMA) -> mish ----------------
__global__ __launch_bounds__(256) void stage1_kernel(
    const float* __restrict__ inputs, const float* __restrict__ sku,
    const float* __restrict__ ln_g, const float* __restrict__ ln_b,
    const float* __restrict__ attnw, const float* __restrict__ cps,
    const u16* __restrict__ WhT, u16* __restrict__ agg, u16* __restrict__ skub)
{
  __shared__ __align__(16) float in_l[256];
  __shared__ __align__(16) float cps_l[512];
  __shared__ __align__(16) float gam_l[512];
  __shared__ __align__(16) float bet_l[512];
  __shared__ float aw_l[16];
  __shared__ __align__(16) u16 at_l[16*16*32];   // [h][b16][c32]
  __shared__ __align__(16) u16 ot_l[16*512];     // [b16][512]

  const int t = threadIdx.x;
  const long bb = (long)blockIdx.x * 16;

  in_l[t] = inputs[bb*16 + t];
  cps_l[t] = cps[t];       cps_l[t+256] = cps[t+256];
  gam_l[t] = ln_g[t];      gam_l[t+256] = ln_g[t+256];
  bet_l[t] = ln_b[t];      bet_l[t+256] = ln_b[t+256];
  if (t < 16) aw_l[t] = attnw[t];
  { // sku -> bf16 (16 rows x 64)
    const f32x4 sv = *(const f32x4*)&sku[bb*64 + t*4];
    unsigned lo = (unsigned)f2bf(sv.x) | ((unsigned)f2bf(sv.y) << 16);
    unsigned hi = (unsigned)f2bf(sv.z) | ((unsigned)f2bf(sv.w) << 16);
    unsigned long long v = (unsigned long long)lo | ((unsigned long long)hi << 32);
    *(unsigned long long*)&skub[bb*64 + t*4] = v;
  }
  __syncthreads();

  const int h = t >> 4, bi = t & 15;
  const float x = in_l[bi*16 + h];
  float nrm[NC], pw[NC];
  float s1 = 0.f;
#pragma unroll
  for (int c = 0; c < NC; c++){ float f = fmaxf(x - cps_l[h*NC + c], 0.f); nrm[c] = f; s1 += f; }
  const float mu = s1 * (1.f/NC);
  float s2 = 0.f;
#pragma unroll
  for (int c = 0; c < NC; c++){ float d = nrm[c] - mu; s2 += d*d; }
  const float rs = rsqrtf(s2 * (1.f/NC) + 1e-3f);
  const float aw = aw_l[h] * (1.0f/0.7f);
  float lmax = -1e30f;
#pragma unroll
  for (int c = 0; c < NC; c++){
    float nv = (nrm[c] - mu) * rs * gam_l[h*NC + c] + bet_l[h*NC + c];
    nrm[c] = nv;
    lmax = fmaxf(lmax, nv * aw);
  }
  float ps = 0.f;
#pragma unroll
  for (int c = 0; c < NC; c++){ float p = __expf(nrm[c]*aw - lmax); pw[c] = p; ps += p; }
  const float invs = 1.f / ps;
#pragma unroll
  for (int c = 0; c < NC; c += 2){
    unsigned pk = (unsigned)f2bf(nrm[c]*pw[c]*invs) | ((unsigned)f2bf(nrm[c+1]*pw[c+1]*invs) << 16);
    *(unsigned*)&at_l[h*512 + bi*32 + c] = pk;
  }
  __syncthreads();

  const int wv = t >> 6, ln = t & 63;
  const int lrow = ln & 15, lq = ln >> 4;
#pragma unroll
  for (int q = 0; q < 4; q++){
    const int hh = wv*4 + q;
    short8 af  = *(const short8*)&at_l[hh*512 + lrow*32 + lq*8];
    short8 bf0 = *(const short8*)&WhT[hh*1024 + lrow*32 + lq*8];
    short8 bf1 = *(const short8*)&WhT[hh*1024 + (16 + lrow)*32 + lq*8];
    f32x4 acc0 = {0.f,0.f,0.f,0.f}, acc1 = {0.f,0.f,0.f,0.f};
    acc0 = __builtin_amdgcn_mfma_f32_16x16x32_bf16(af, bf0, acc0, 0, 0, 0);
    acc1 = __builtin_amdgcn_mfma_f32_16x16x32_bf16(af, bf1, acc1, 0, 0, 0);
#pragma unroll
    for (int r = 0; r < 4; r++){
      const int br = lq*4 + r;
      ot_l[br*512 + hh*32 + lrow]      = f2bf(mishf(acc0[r]));
      ot_l[br*512 + hh*32 + 16 + lrow] = f2bf(mishf(acc1[r]));
    }
  }
  __syncthreads();
  {
    const int row = t >> 4, c16 = t & 15;
    const i32x4* src = (const i32x4*)&ot_l[row*512 + c16*32];
    i32x4* dst = (i32x4*)&agg[(bb + row)*512 + c16*32];
#pragma unroll
    for (int j = 0; j < 4; j++) dst[j] = src[j];
  }
}

// ---------------- GEMM skeleton: [M x KD] (bf16) @ BtT [512 x KD] -> epilogue -> 16-bit [M x 512]
// EPI: 0 = mish (bf16 out), 1 = *(1/0.7) (fp16 out), 2 = sigmoid (fp16 out)
template<int KD, int EPI>
__global__ __launch_bounds__(256, 2) void gemm_k(
    const u16* __restrict__ A, const u16* __restrict__ Bt, u16* __restrict__ outp)
{
  __shared__ __align__(16) u16 As[2][128*32];
  __shared__ __align__(16) u16 Bs[2][128*32];
  const int t = threadIdx.x, wv = t >> 6, ln = t & 63;
  const long m0 = (long)(blockIdx.x >> 2) * 128;
  const int n0 = (blockIdx.x & 3) * 128;
  const int lrow = ln & 15, lq = ln >> 4;
  const int wm = wv >> 1, wn = wv & 1;

  auto stage = [&](int buf, int kt){
#pragma unroll
    for (int p = 0; p < 2; p++){
      const int chunk = p*256 + wv*64 + ln;
      const int mm = chunk >> 2, kc = chunk & 3;
      GLLDS(&A[(m0 + mm)*KD + kt + kc*8],        &As[buf][(p*256 + wv*64)*8]);
      GLLDS(&Bt[(long)(n0 + mm)*KD + kt + kc*8], &Bs[buf][(p*256 + wv*64)*8]);
    }
  };

  f32x4 acc[4][4] = {};
  stage(0, 0);
  const int NK = KD / 32;
  for (int ks = 0; ks < NK; ks++){
    const int cur = ks & 1;
    __syncthreads();
    if (ks + 1 < NK) stage(cur ^ 1, (ks + 1)*32);
    short8 a[4], b[4];
#pragma unroll
    for (int i = 0; i < 4; i++){
      a[i] = *(const short8*)&As[cur][(wm*64 + i*16 + lrow)*32 + lq*8];
      b[i] = *(const short8*)&Bs[cur][(wn*64 + i*16 + lrow)*32 + lq*8];
    }
#pragma unroll
    for (int i = 0; i < 4; i++)
#pragma unroll
      for (int j = 0; j < 4; j++)
        acc[i][j] = __builtin_amdgcn_mfma_f32_16x16x32_bf16(a[i], b[j], acc[i][j], 0, 0, 0);
  }
#pragma unroll
  for (int i = 0; i < 4; i++)
#pragma unroll
    for (int j = 0; j < 4; j++)
#pragma unroll
      for (int r = 0; r < 4; r++){
        const long m = m0 + wm*64 + i*16 + lq*4 + r;
        const int n = n0 + wn*64 + j*16 + lrow;
        float v = acc[i][j][r];
        u16 ob;
        if (EPI == 0)      ob = f2bf(mishf(v));
        else if (EPI == 1) ob = f2h(v * (1.0f/0.7f));
        else               ob = f2h(1.f / (1.f + __expf(-v)));
        outp[m*512 + n] = ob;
      }
}

// ---------------- final: softmax(logits) -> out = sum(aggh*attn*beta*Wo) + sku.wWo ----------------
__global__ __launch_bounds__(256) void final_kernel(
    const u16* __restrict__ logits, const u16* __restrict__ aggh,
    const u16* __restrict__ betab, const float* __restrict__ sku,
    const float* __restrict__ Wo, const float* __restrict__ wWo,
    float* __restrict__ outp)
{
  __shared__ float wo_l[512];
  __shared__ float wwo_l[64];
  const int t = threadIdx.x;
  wo_l[t] = Wo[t]; wo_l[t+256] = Wo[t+256];
  if (t < 64) wwo_l[t] = wWo[t];
  __syncthreads();
  const int wv = t >> 6, ln = t & 63;
  const long rbase = (long)blockIdx.x * 32 + wv*8;
#pragma unroll 1
  for (int j = 0; j < 8; j++){
    const long row = rbase + j;
    i32x4 lv = *(const i32x4*)&logits[row*512 + ln*8];
    const u16* lp = (const u16*)&lv;
    float l[8];
#pragma unroll
    for (int q = 0; q < 8; q++) l[q] = h2f(lp[q]);
    float mx = l[0];
#pragma unroll
    for (int q = 1; q < 8; q++) mx = fmaxf(mx, l[q]);
#pragma unroll
    for (int s = 1; s < 64; s <<= 1) mx = fmaxf(mx, __shfl_xor(mx, s));
    float p[8]; float ps = 0.f;
#pragma unroll
    for (int q = 0; q < 8; q++){ p[q] = __expf(l[q] - mx); ps += p[q]; }
#pragma unroll
    for (int s = 1; s < 64; s <<= 1) ps += __shfl_xor(ps, s);
    const float invs = 1.f / ps;
    i32x4 av = *(const i32x4*)&aggh[row*512 + ln*8];
    i32x4 bv = *(const i32x4*)&betab[row*512 + ln*8];
    const u16* ap = (const u16*)&av;
    const u16* bp = (const u16*)&bv;
    float acc = 0.f;
#pragma unroll
    for (int q = 0; q < 8; q++)
      acc += bf2f(ap[q]) * p[q] * h2f(bp[q]) * wo_l[ln*8 + q];
    acc *= invs;
    acc += sku[row*64 + ln] * wwo_l[ln];
#pragma unroll
    for (int s = 1; s < 64; s <<= 1) acc += __shfl_xor(acc, s);
    if (ln == 0) outp[row] = acc;
  }
}

__global__ void ws_too_small(float* o, float v){ o[(long)blockIdx.x*256 + threadIdx.x] = v; }

extern "C" void kernel_launch(void* const* d_in, const int* in_sizes, int n_in,
                              void* d_out, int out_size, void* d_ws, size_t ws_size,
                              hipStream_t stream)
{
  const float* inputs = (const float*)d_in[0];
  const float* sku    = (const float*)d_in[1];
  const float* deltas = (const float*)d_in[2];
  const float* ln_g   = (const float*)d_in[3];
  const float* ln_b   = (const float*)d_in[4];
  const float* attnw  = (const float*)d_in[5];
  const float* Wh     = (const float*)d_in[6];
  const float* Wah    = (const float*)d_in[7];
  const float* Waa    = (const float*)d_in[8];
  const float* Wb     = (const float*)d_in[9];
  const float* Wa     = (const float*)d_in[10];
  const float* Wo     = (const float*)d_in[11];
  float* outp = (float*)d_out;

  // workspace layout (bytes) — chunked over batch (2 x 65536 rows) to fit 256 MiB
  const size_t OFF_CPS  = 0;                      // 2048
  const size_t OFF_WWO  = 2048;                   // 256
  const size_t OFF_WAHT = 4096;                   // 524288
  const size_t OFF_WAAT = OFF_WAHT + 524288;      // 524288
  const size_t OFF_WBT  = OFF_WAAT + 524288;      // 65536
  const size_t OFF_WHT  = OFF_WBT  + 65536;       // 32768
  const size_t OFF_SKUB = OFF_WHT  + 32768;       // 8 MB  (chunk)
  const size_t OFF_AGG  = OFF_SKUB + (size_t)CHUNK*64*2;    // 64 MB (chunk)
  const size_t OFF_AGH  = OFF_AGG  + (size_t)CHUNK*512*2;   // 64 MB (chunk)
  const size_t OFF_LOG  = OFF_AGH  + (size_t)CHUNK*512*2;   // 64 MB (chunk)
  const size_t NEED     = OFF_LOG  + (size_t)CHUNK*512*2;   // ~201 MB

  if (ws_size < NEED){
    hipLaunchKernelGGL(ws_too_small, dim3(B_TOT/256), dim3(256), 0, stream,
                       outp, -(float)(ws_size >> 20));
    return;
  }

  char* ws = (char*)d_ws;
  float* cps  = (float*)(ws + OFF_CPS);
  float* wWo  = (float*)(ws + OFF_WWO);
  u16* WahT   = (u16*)(ws + OFF_WAHT);
  u16* WaaT   = (u16*)(ws + OFF_WAAT);
  u16* WbT    = (u16*)(ws + OFF_WBT);
  u16* WhT    = (u16*)(ws + OFF_WHT);
  u16* skub   = (u16*)(ws + OFF_SKUB);
  u16* agg    = (u16*)(ws + OFF_AGG);
  u16* aggh   = (u16*)(ws + OFF_AGH);
  u16* logits = (u16*)(ws + OFF_LOG);
  u16* betab  = agg;   // agg is dead after gemm1; beta GEMM runs after it

  hipLaunchKernelGGL(prep_small, dim3(1), dim3(128), 0, stream, deltas, Wa, Wo, cps, wWo);
  hipLaunchKernelGGL(prep_convert, dim3(2240), dim3(256), 0, stream,
                     Wah, Waa, Wb, Wh, WahT, WaaT, WbT, WhT);

  for (int ch = 0; ch < B_TOT / CHUNK; ch++){
    const float* in_c  = inputs + (size_t)ch * CHUNK * 16;
    const float* sku_c = sku    + (size_t)ch * CHUNK * 64;
    float* out_c       = outp   + (size_t)ch * CHUNK;

    hipLaunchKernelGGL(stage1_kernel, dim3(CHUNK/16), dim3(256), 0, stream,
                       in_c, sku_c, ln_g, ln_b, attnw, cps, WhT, agg, skub);
    hipLaunchKernelGGL((gemm_k<512,0>), dim3((CHUNK/128)*4), dim3(256), 0, stream, agg,  WahT, aggh);
    hipLaunchKernelGGL((gemm_k<64,2>),  dim3((CHUNK/128)*4), dim3(256), 0, stream, skub, WbT,  betab);
    hipLaunchKernelGGL((gemm_k<512,1>), dim3((CHUNK/128)*4), dim3(256), 0, stream, aggh, WaaT, logits);
    hipLaunchKernelGGL(final_kernel, dim3(CHUNK/32), dim3(256), 0, stream,
                       logits, aggh, betab, sku_c, Wo, wWo, out_c);
  }
}